// Round 1
// baseline (99.705 us; speedup 1.0000x reference)
//
#include <hip/hip_runtime.h>

// BallQLoss: ball_query(pc, r=0.2, k=16) against itself + L1 grouping loss.
// pc: (4, 4096, 3) f32, mask: (4, 4096, 30) f32 -> scalar f32.
// One wave (64 lanes) per query point; ballot-based ordered first-16 selection
// with early exit; lanes 0..29 handle the 30 channels of each L1 diff.

#define BQ_B 4
#define BQ_N 4096
#define BQ_C 30
#define BQ_K 16
#define BQ_R2 0.04f
#define WAVES_PER_BLOCK 8
#define BLOCK_T (WAVES_PER_BLOCK * 64)

__global__ __launch_bounds__(BLOCK_T) void ballq_loss_kernel(
    const float* __restrict__ pc,    // (B, N, 3)
    const float* __restrict__ mask,  // (B, N, C)
    float* __restrict__ out)         // scalar
{
    const int tid  = threadIdx.x;
    const int lane = tid & 63;
    const int wave = tid >> 6;
    const int query = blockIdx.x * WAVES_PER_BLOCK + wave;  // [0, B*N)
    const int b = query >> 12;        // / N
    const int n = query & (BQ_N - 1); // % N

    const float* pcb   = pc   + (size_t)b * BQ_N * 3;
    const float* maskb = mask + (size_t)b * BQ_N * BQ_C;

    const float qx = pcb[n * 3 + 0];
    const float qy = pcb[n * 3 + 1];
    const float qz = pcb[n * 3 + 2];
    const float qv = (lane < BQ_C) ? maskb[n * BQ_C + lane] : 0.f;

    int   found = 0;
    int   first = -1;
    float lsum  = 0.f;

    // Scan candidates in ascending index order, 64 at a time.
    for (int base = 0; base < BQ_N && found < BQ_K; base += 64) {
        const int m = base + lane;
        const float dx = pcb[m * 3 + 0] - qx;
        const float dy = pcb[m * 3 + 1] - qy;
        const float dz = pcb[m * 3 + 2] - qz;
        const float d2 = dx * dx + dy * dy + dz * dz;
        unsigned long long bal = __ballot(d2 < BQ_R2);
        // Peel lowest set bits (ascending index order) until k found.
        while (bal && found < BQ_K) {
            const int bit = __builtin_ctzll(bal);
            bal &= bal - 1;
            const int msel = base + bit;
            if (found == 0) first = msel;
            if (lane < BQ_C)
                lsum += fabsf(qv - maskb[msel * BQ_C + lane]);
            ++found;
        }
    }
    // Pad remaining slots with the first found index (reference semantics).
    if (found < BQ_K && first >= 0 && lane < BQ_C)
        lsum += (float)(BQ_K - found) * fabsf(qv - maskb[first * BQ_C + lane]);

    // Wave reduction (64 lanes).
    for (int off = 32; off > 0; off >>= 1)
        lsum += __shfl_xor(lsum, off, 64);

    __shared__ float wsum[WAVES_PER_BLOCK];
    if (lane == 0) wsum[wave] = lsum;
    __syncthreads();
    if (tid == 0) {
        float s = 0.f;
        #pragma unroll
        for (int w = 0; w < WAVES_PER_BLOCK; ++w) s += wsum[w];
        atomicAdd(out, s * (1.0f / ((float)BQ_B * BQ_N * BQ_K)));
    }
}

extern "C" void kernel_launch(void* const* d_in, const int* in_sizes, int n_in,
                              void* d_out, int out_size, void* d_ws, size_t ws_size,
                              hipStream_t stream) {
    const float* pc   = (const float*)d_in[0];  // (4, 4096, 3)
    const float* mask = (const float*)d_in[1];  // (4, 4096, 30)
    float* out = (float*)d_out;

    // d_out is poisoned 0xAA before every timed launch — zero it (async, capture-safe).
    hipMemsetAsync(out, 0, sizeof(float), stream);

    const int n_query = BQ_B * BQ_N;
    const int grid = n_query / WAVES_PER_BLOCK;  // 2048 blocks
    ballq_loss_kernel<<<grid, BLOCK_T, 0, stream>>>(pc, mask, out);
}